// Round 23
// baseline (1051.540 us; speedup 1.0000x reference)
//
#include <hip/hip_runtime.h>

#define T_DIM 2048
#define B_DIM 32
#define D_DIM 128
#define H_DIM 512
#define L_DIM 6
#define C_DIM 10
#define BN_EPS 1e-5f

constexpr int TB = T_DIM * B_DIM;           // 65536 rows (t-major, then b)
constexpr size_t TBH = (size_t)TB * H_DIM;  // 33,554,432 elements
constexpr size_t PKN = TBH / 2;             // packed u32 count (64 MB)
constexpr int NCH_CHAINS = B_DIM * H_DIM;   // 16384 chains
constexpr int NSEG = 16;                    // segments per chain
constexpr int SEGI = (T_DIM / 2) / NSEG;    // 64 packed items per segment

typedef short s16x8 __attribute__((ext_vector_type(8)));
typedef float f32x16 __attribute__((ext_vector_type(16)));

// ---- bf16 helpers (bit-level, RNE) ----
__device__ inline unsigned short f2bf(float f) {
  unsigned u = __float_as_uint(f);
  unsigned r = (u + 0x7FFFu + ((u >> 16) & 1u)) >> 16;
  return (unsigned short)r;
}
__device__ inline float bf2f(unsigned short b) {
  return __uint_as_float((unsigned)b << 16);
}

// De-interleave 8 packed u32 (evenT | oddT<<16) into two planar s16x8 in LDS.
__device__ inline void destage(uint4 q0, uint4 q1, unsigned short* dlo,
                               unsigned short* dhi) {
  uint4 lo, hi;
  lo.x = __builtin_amdgcn_perm(q0.y, q0.x, 0x05040100u);
  lo.y = __builtin_amdgcn_perm(q0.w, q0.z, 0x05040100u);
  lo.z = __builtin_amdgcn_perm(q1.y, q1.x, 0x05040100u);
  lo.w = __builtin_amdgcn_perm(q1.w, q1.z, 0x05040100u);
  hi.x = __builtin_amdgcn_perm(q0.y, q0.x, 0x07060302u);
  hi.y = __builtin_amdgcn_perm(q0.w, q0.z, 0x07060302u);
  hi.z = __builtin_amdgcn_perm(q1.y, q1.x, 0x07060302u);
  hi.w = __builtin_amdgcn_perm(q1.w, q1.z, 0x07060302u);
  *(uint4*)dlo = lo;
  *(uint4*)dhi = hi;
}

// ---------------------------------------------------------------------------
// bf16 MFMA GEMM over t-pair-packed activations (out-of-place ping-pong):
//   z[t,b,o] = sum_k s[t,b,k] * W[o,k] + bias[o],  N = 512 fixed.
// 512 threads (8 waves), wave = 64 rows x 64 cols; planar-bf16 LDS staging
// (store-side destage), 1-term MFMA with single bf16 W in pre-swizzled
// fragment order. R23: RING-8 W prefetch -- ring-4's 3-step lookahead
// (~96 cyc) was under L2 latency (~200+ cyc), leaving ~100 cyc exposed per
// K-step (the 3.2x gap between 43.5us observed and the 13.8us MFMA floor).
// 7-step lookahead (~224 cyc) covers it; ring = 64 VGPR, total ~96-100,
// still <=128 so 4 waves/SIMD hold. Coalesced epilogue via LDS funnel.
// W fragment layout: elem (o,k) at ((c32*NIT+itg)*64 + kg*32 + r31)*8 + j.
// Also zeroes stats[0..1023] from block 0 (bn_fold precedes in stream order).
// ---------------------------------------------------------------------------
#define ROWS 64

template <int K, int BKC, bool PACKED_IN>
__global__ __launch_bounds__(512, 4) void gemm_mfma(
    const void* src, const unsigned short* __restrict__ Whi,
    const float* __restrict__ bias, uint* __restrict__ dstP, float* stats) {
  constexpr int NC = K / BKC;      // 2 (layer 0) or 4 (K=512)
  constexpr int NITC = BKC / 16;   // MFMA k-steps per chunk
  constexpr int NIT = K / 16;
  constexpr int GM = BKC / 8 - 1;  // granule swizzle mask
  __shared__ __align__(16) unsigned short AhS[2][ROWS * BKC];

  const int tid = threadIdx.x;
  if (blockIdx.x == 0) {  // fold zero_stats into the GEMM
    stats[tid] = 0.f;
    stats[tid + 512] = 0.f;
  }
  const int lane = tid & 63;
  const int wave = tid >> 6;  // 0..7 = col-group of 64
  const int r31 = lane & 31;
  const int kg = lane >> 5;

  const size_t pbase = (size_t)blockIdx.x * 16384;  // block's u32 region
  const uint* srcP = (const uint*)src;
  const float* srcF = (const float*)src;
  const size_t row0 = (size_t)blockIdx.x * ROWS;  // f32-path row base

  const unsigned short* pWh0 =
      Whi + ((size_t)(wave * 2 + 0) * NIT * 64 + lane) * 8;
  const unsigned short* pWh1 =
      Whi + ((size_t)(wave * 2 + 1) * NIT * 64 + lane) * 8;

  const int sr0 = tid >> 4, sk0 = tid & 15;
  const int ss0 = sr0 * BKC + ((sk0 ^ (sr0 & GM)) << 3);
  const int ss1 = (sr0 + 32) * BKC + ((sk0 ^ ((sr0 + 32) & GM)) << 3);
  const int srf = tid >> 3, skf = tid & 7;
  const int ssf = srf * BKC + ((skf ^ (srf & GM)) << 3);

  auto cvt8 = [&](float4 a, float4 b) {
    float vv[8] = {a.x, a.y, a.z, a.w, b.x, b.y, b.z, b.w};
    s16x8 hi;
#pragma unroll
    for (int j = 0; j < 8; ++j) hi[j] = (short)f2bf(vv[j]);
    return hi;
  };

  // ---- prologue: stage chunk 0 ----
  if (PACKED_IN) {
    uint4 q0 = *(const uint4*)(srcP + pbase + sr0 * 512 + sk0 * 8);
    uint4 q1 = *(const uint4*)(srcP + pbase + sr0 * 512 + sk0 * 8 + 4);
    destage(q0, q1, &AhS[0][ss0], &AhS[0][ss1]);
  } else {
    const size_t g = (row0 + srf) * K + skf * 8;
    *(s16x8*)&AhS[0][ssf] =
        cvt8(*(const float4*)(srcF + g), *(const float4*)(srcF + g + 4));
  }
  // ---- W ring prologue: fragments itg=0..6 into slots 0..6 ----
  s16x8 whr[8][2];
#pragma unroll
  for (int s = 0; s < 7; ++s) {
    whr[s][0] = *(const s16x8*)(pWh0 + (size_t)s * 512);
    whr[s][1] = *(const s16x8*)(pWh1 + (size_t)s * 512);
  }
  __syncthreads();

  f32x16 acc[2][2] = {};
  uint4 q0, q1;   // in-flight next-chunk A (packed)
  float4 f0, f1;  // in-flight next-chunk A (f32)
#pragma unroll
  for (int c = 0; c < NC; ++c) {
    if (c + 1 < NC) {  // issue next chunk's loads (hide under MFMAs)
      if (PACKED_IN) {
        q0 = *(const uint4*)(srcP + pbase + sr0 * 512 + (c + 1) * BKC +
                             sk0 * 8);
        q1 = *(const uint4*)(srcP + pbase + sr0 * 512 + (c + 1) * BKC +
                             sk0 * 8 + 4);
      } else {
        const size_t g = (row0 + srf) * K + (c + 1) * BKC + skf * 8;
        f0 = *(const float4*)(srcF + g);
        f1 = *(const float4*)(srcF + g + 4);
      }
    }
    const int bsel = c & 1;
#pragma unroll
    for (int it = 0; it < NITC; ++it) {
      const int itg = c * NITC + it;
      const int sl = itg & 7;
      if (itg + 7 < NIT) {  // ring-8 W prefetch (7-step lookahead)
        const int sp = (itg + 7) & 7;
        whr[sp][0] = *(const s16x8*)(pWh0 + (size_t)(itg + 7) * 512);
        whr[sp][1] = *(const s16x8*)(pWh1 + (size_t)(itg + 7) * 512);
      }
      const int gi = it * 2 + kg;
      s16x8 ah[2];
#pragma unroll
      for (int rf = 0; rf < 2; ++rf) {
        const int row = rf * 32 + r31;
        ah[rf] =
            *(const s16x8*)&AhS[bsel][row * BKC + ((gi ^ (row & GM)) << 3)];
      }
#pragma unroll
      for (int cf = 0; cf < 2; ++cf)
#pragma unroll
        for (int rf = 0; rf < 2; ++rf)
          acc[rf][cf] = __builtin_amdgcn_mfma_f32_32x32x16_bf16(
              ah[rf], whr[sl][cf], acc[rf][cf], 0, 0, 0);
    }
    if (c + 1 < NC) {  // stage next chunk into the other LDS buffer
      const int nb = (c + 1) & 1;
      if (PACKED_IN) {
        destage(q0, q1, &AhS[nb][ss0], &AhS[nb][ss1]);
      } else {
        *(s16x8*)&AhS[nb][ssf] = cvt8(f0, f1);
      }
      __syncthreads();
    }
  }

  // ---- epilogue (coalesced via LDS funnel) ----
  {
    uint* Cs = (uint*)&AhS[0][0];
    constexpr int CAP = ROWS * BKC;
    constexpr int RP = CAP / 512;
    constexpr int NP = 32 / RP;
    constexpr int NQ = CAP / 2048;
    const int o0 = wave * 64 + r31;
    const float bb0 = bias[o0];
    const float bb1 = bias[o0 + 32];
    __syncthreads();
#pragma unroll
    for (int p = 0; p < NP; ++p) {
#pragma unroll
      for (int j = 0; j < RP / 2; ++j) {
        const int r = p * (RP / 2) + j;
        const int mb = (r & 3) + 8 * (r >> 2) + 4 * kg;
        const int lr = mb - p * RP;
        const float e0 = acc[0][0][r] + bb0;
        const float d0 = acc[1][0][r] + bb0;
        const float e1 = acc[0][1][r] + bb1;
        const float d1 = acc[1][1][r] + bb1;
        Cs[lr * 512 + o0] = (uint)f2bf(e0) | ((uint)f2bf(d0) << 16);
        Cs[lr * 512 + o0 + 32] = (uint)f2bf(e1) | ((uint)f2bf(d1) << 16);
      }
      __syncthreads();
#pragma unroll
      for (int qd = 0; qd < NQ; ++qd) {
        uint4 v = *(const uint4*)&Cs[qd * 2048 + tid * 4];
        *(uint4*)&dstP[pbase + (size_t)p * CAP + qd * 2048 + tid * 4] = v;
      }
      if (p + 1 < NP) __syncthreads();
    }
  }
}

// ---------------------------------------------------------------------------
// R22 FUSED segmented scan (R23: +LDS-reduced stats atomics).
// h_t = max(z_t + u h_{t-1}, 0) composes as F(h)=max(A+B h, G).
// Block = 64 consecutive chains x all 16 segments (1024 threads, 16 waves;
// wave = one segment x 64 chains -> coalesced 256B/instr). Per thread:
// load segment's 64 packed u32 into REGISTERS, fold (A,G), LDS-exchange,
// serial exclusive combine with B=u^128, replay from registers, write
// packed bf16 s. Stats reduced across the 16 segments in LDS first ->
// 16x fewer atomics (2048 -> 128 per block over 512 hot addresses).
// ---------------------------------------------------------------------------
__global__ __launch_bounds__(1024, 4) void indrnn_scan_seg(
    const uint* __restrict__ z, uint* __restrict__ sdst,
    const float* __restrict__ u, float* __restrict__ stats) {
  __shared__ float Als[NSEG * 64];
  __shared__ float Gls[NSEG * 64];
  const int tid = threadIdx.x;
  const int j = tid >> 6;   // segment 0..15 (wave-uniform)
  const int cl = tid & 63;  // chain-in-block
  const int c = blockIdx.x * 64 + cl;
  const int hch = c & (H_DIM - 1);
  const float uu = u[hch];
  const uint* ps = z + c + (size_t)j * SEGI * NCH_CHAINS;
  uint* pd = sdst + c + (size_t)j * SEGI * NCH_CHAINS;

  // ---- load whole segment into registers ----
  uint v[SEGI];
#pragma unroll
  for (int q = 0; q < SEGI; ++q) v[q] = ps[(size_t)q * NCH_CHAINS];

  // ---- phase A: fold segment map (A = linear part, G = floor) ----
  float A = 0.f, G = -1.0e30f;
#pragma unroll
  for (int q = 0; q < SEGI; ++q) {
    const uint pk = v[q];
    const float ze = __uint_as_float(pk << 16);
    const float zo = __uint_as_float(pk & 0xffff0000u);
    A = fmaf(uu, A, ze);
    G = fmaxf(fmaf(uu, G, ze), 0.f);
    A = fmaf(uu, A, zo);
    G = fmaxf(fmaf(uu, G, zo), 0.f);
  }
  Als[tid] = A;  // row j, col cl
  Gls[tid] = G;
  __syncthreads();

  // ---- exclusive combine: incoming h for segment j ----
  float B = uu;
#pragma unroll
  for (int q = 0; q < 7; ++q) B *= B;  // u^128
  float hh = 0.f;
  for (int jp = 0; jp < j; ++jp)  // wave-uniform trip count
    hh = fmaxf(fmaf(B, hh, Als[jp * 64 + cl]), Gls[jp * 64 + cl]);
  __syncthreads();  // all combine reads done before Als/Gls reuse below

  // ---- phase C: replay from registers, write packed bf16 s ----
  float sum = 0.f, sumsq = 0.f;
#pragma unroll
  for (int q = 0; q < SEGI; ++q) {
    const uint pk = v[q];
    const float ze = __uint_as_float(pk << 16);
    const float zo = __uint_as_float(pk & 0xffff0000u);
    hh = fmaxf(ze + uu * hh, 0.f);
    const unsigned short he = f2bf(hh);
    const float se = bf2f(he);
    sum += se;
    sumsq += se * se;
    hh = fmaxf(zo + uu * hh, 0.f);
    const unsigned short ho = f2bf(hh);
    const float so = bf2f(ho);
    sum += so;
    sumsq += so * so;
    pd[(size_t)q * NCH_CHAINS] = (uint)he | ((uint)ho << 16);
  }
  // ---- stats: reduce across segments in LDS, 1 atomic pair per chain ----
  Als[tid] = sum;
  Gls[tid] = sumsq;
  __syncthreads();
  if (j == 0) {
    float ts = 0.f, tq = 0.f;
#pragma unroll
    for (int jp = 0; jp < NSEG; ++jp) {
      ts += Als[jp * 64 + cl];
      tq += Gls[jp * 64 + cl];
    }
    atomicAdd(&stats[hch], ts);
    atomicAdd(&stats[H_DIM + hch], tq);
  }
}

__global__ __launch_bounds__(64) void fill_sentinel(float* __restrict__ out,
                                                    int n) {
  for (int i = threadIdx.x; i < n; i += 64) out[i] = 1.0e6f;
}

// ---------------------------------------------------------------------------
// Convert raw f32 weights (layer 0) to bf16 in fragment-swizzled order.
// ---------------------------------------------------------------------------
template <int K>
__global__ __launch_bounds__(256) void convert_w(
    const float* __restrict__ W, unsigned short* __restrict__ Whi) {
  constexpr int NIT = K / 16;
  int i = blockIdx.x * 256 + threadIdx.x;
  if (i < H_DIM * K) {
    int o = i / K, k = i % K;
    size_t idx =
        ((size_t)((o >> 5) * NIT + (k >> 4)) * 64 + ((k >> 3) & 1) * 32 +
         (o & 31)) * 8 + (k & 7);
    Whi[idx] = f2bf(W[i]);
  }
}

// ---------------------------------------------------------------------------
// Fold BN of previous layer into next layer's weights, emit swizzled bf16.
// ---------------------------------------------------------------------------
__global__ __launch_bounds__(256) void bn_fold(
    const float* __restrict__ stats, const float* __restrict__ gamma,
    const float* __restrict__ beta, const float* __restrict__ Wn,
    const float* __restrict__ bn, unsigned short* __restrict__ Whi,
    float* __restrict__ bf) {
  constexpr int NIT = H_DIM / 16;
  const int o = blockIdx.x;
  const int tid = threadIdx.x;
  constexpr float invTB = 1.f / (float)(T_DIM * B_DIM);
  float part = 0.f;
  for (int i = tid; i < H_DIM; i += 256) {
    float mean = stats[i] * invTB;
    float var = stats[H_DIM + i] * invTB - mean * mean;
    float a = gamma[i] * rsqrtf(var + BN_EPS);
    float c = beta[i] - mean * a;
    float w = Wn[(size_t)o * H_DIM + i];
    size_t idx =
        ((size_t)((o >> 5) * NIT + (i >> 4)) * 64 + ((i >> 3) & 1) * 32 +
         (o & 31)) * 8 + (i & 7);
    Whi[idx] = f2bf(w * a);
    part += w * c;
  }
  __shared__ float red[256];
  red[tid] = part;
  __syncthreads();
  for (int s = 128; s > 0; s >>= 1) {
    if (tid < s) red[tid] += red[tid + s];
    __syncthreads();
  }
  if (tid == 0) bf[o] = bn[o] + red[0];
}

// ---------------------------------------------------------------------------
// Final: out[b,c] = sum_i (s5[T-1,b,i]*a5[i] + c5[i]) * Wout[c,i] + bout[c]
// ---------------------------------------------------------------------------
__global__ __launch_bounds__(64) void final_out(const uint* __restrict__ s5,
                                                const float* __restrict__ stats,
                                                const float* __restrict__ gamma,
                                                const float* __restrict__ beta,
                                                const float* __restrict__ Wout,
                                                const float* __restrict__ bout,
                                                float* __restrict__ out) {
  const int b = blockIdx.x / C_DIM, cls = blockIdx.x % C_DIM;
  const int lane = threadIdx.x;
  constexpr float invTB = 1.f / (float)(T_DIM * B_DIM);
  const uint* srow =
      s5 + (size_t)(T_DIM / 2 - 1) * B_DIM * H_DIM + (size_t)b * H_DIM;
  float part = 0.f;
  for (int i = lane; i < H_DIM; i += 64) {
    float mean = stats[i] * invTB;
    float var = stats[H_DIM + i] * invTB - mean * mean;
    float a = gamma[i] * rsqrtf(var + BN_EPS);
    float c = beta[i] - mean * a;
    float sval = __uint_as_float(srow[i] & 0xffff0000u);
    part += (sval * a + c) * Wout[(size_t)cls * H_DIM + i];
  }
#pragma unroll
  for (int off = 32; off > 0; off >>= 1) part += __shfl_down(part, off);
  if (lane == 0) out[b * C_DIM + cls] = part + bout[cls];
}

// ---------------------------------------------------------------------------
extern "C" void kernel_launch(void* const* d_in, const int* in_sizes, int n_in,
                              void* d_out, int out_size, void* d_ws,
                              size_t ws_size, hipStream_t stream) {
  const float* x     = (const float*)d_in[0];
  const float* W0    = (const float*)d_in[1];
  const float* b0    = (const float*)d_in[2];
  const float* Wh    = (const float*)d_in[3];
  const float* bh    = (const float*)d_in[4];
  const float* u     = (const float*)d_in[5];
  const float* gamma = (const float*)d_in[6];
  const float* beta  = (const float*)d_in[7];
  const float* Wout  = (const float*)d_in[8];
  const float* bout  = (const float*)d_in[9];
  float* out = (float*)d_out;

  const size_t need = 2 * PKN * sizeof(uint) +
                      (size_t)H_DIM * H_DIM * sizeof(unsigned short) +
                      3 * H_DIM * sizeof(float);
  if (ws_size < need) {
    fill_sentinel<<<1, 64, 0, stream>>>(out, out_size);
    return;
  }

  uint* bufA = (uint*)d_ws;                             // 64 MB: z
  uint* bufB = bufA + PKN;                              // 64 MB: s
  unsigned short* Whi = (unsigned short*)(bufB + PKN);  // 512 KB
  float* bf = (float*)(Whi + (size_t)H_DIM * H_DIM);    // 2 KB
  float* stats = bf + H_DIM;                            // 4 KB

  const int gemm_blocks = TB / ROWS;        // 1024
  const int scan_blocks = NCH_CHAINS / 64;  // 256 blocks x 1024 threads

  // ---- layer 0: x (f32, K=128, BKC=64 -> NC=2 pipelined) -> bufA (z) ----
  convert_w<D_DIM><<<(H_DIM * D_DIM + 255) / 256, 256, 0, stream>>>(W0, Whi);
  gemm_mfma<D_DIM, 64, false><<<gemm_blocks, 512, 0, stream>>>(x, Whi, b0,
                                                               bufA, stats);
  indrnn_scan_seg<<<scan_blocks, 1024, 0, stream>>>(bufA, bufB, u, stats);

  // ---- layers 1..5: ping-pong (s in B -> z in A -> s in B) ----
  for (int l = 1; l < L_DIM; ++l) {
    const float* ul = u + (size_t)l * H_DIM;
    bn_fold<<<H_DIM, 256, 0, stream>>>(
        stats, gamma + (size_t)(l - 1) * H_DIM, beta + (size_t)(l - 1) * H_DIM,
        Wh + (size_t)(l - 1) * H_DIM * H_DIM, bh + (size_t)(l - 1) * H_DIM,
        Whi, bf);
    gemm_mfma<H_DIM, 128, true><<<gemm_blocks, 512, 0, stream>>>(
        bufB, Whi, bf, bufA, stats);
    indrnn_scan_seg<<<scan_blocks, 1024, 0, stream>>>(bufA, bufB, ul, stats);
  }

  // ---- final projection (BN of layer 5 applied on the fly) ----
  final_out<<<B_DIM * C_DIM, 64, 0, stream>>>(
      bufB, stats, gamma + 5 * (size_t)H_DIM, beta + 5 * (size_t)H_DIM, Wout,
      bout, out);
}

// Round 24
// 417.240 us; speedup vs baseline: 2.5202x; 2.5202x over previous
//
#include <hip/hip_runtime.h>

#define T_DIM 2048
#define B_DIM 32
#define D_DIM 128
#define H_DIM 512
#define L_DIM 6
#define C_DIM 10
#define BN_EPS 1e-5f

constexpr int TB = T_DIM * B_DIM;           // 65536 rows (t-major, then b)
constexpr size_t TBH = (size_t)TB * H_DIM;  // 33,554,432 elements
constexpr size_t PKN = TBH / 2;             // packed u32 count (64 MB)
constexpr int NCH_CHAINS = B_DIM * H_DIM;   // 16384 chains
constexpr int NSEG = 16;                    // segments per chain
constexpr int SEGI = (T_DIM / 2) / NSEG;    // 64 packed items per segment

typedef short s16x8 __attribute__((ext_vector_type(8)));
typedef float f32x16 __attribute__((ext_vector_type(16)));

// ---- bf16 helpers (bit-level, RNE) ----
__device__ inline unsigned short f2bf(float f) {
  unsigned u = __float_as_uint(f);
  unsigned r = (u + 0x7FFFu + ((u >> 16) & 1u)) >> 16;
  return (unsigned short)r;
}
__device__ inline float bf2f(unsigned short b) {
  return __uint_as_float((unsigned)b << 16);
}

// De-interleave 8 packed u32 (evenT | oddT<<16) into two planar s16x8 in LDS.
__device__ inline void destage(uint4 q0, uint4 q1, unsigned short* dlo,
                               unsigned short* dhi) {
  uint4 lo, hi;
  lo.x = __builtin_amdgcn_perm(q0.y, q0.x, 0x05040100u);
  lo.y = __builtin_amdgcn_perm(q0.w, q0.z, 0x05040100u);
  lo.z = __builtin_amdgcn_perm(q1.y, q1.x, 0x05040100u);
  lo.w = __builtin_amdgcn_perm(q1.w, q1.z, 0x05040100u);
  hi.x = __builtin_amdgcn_perm(q0.y, q0.x, 0x07060302u);
  hi.y = __builtin_amdgcn_perm(q0.w, q0.z, 0x07060302u);
  hi.z = __builtin_amdgcn_perm(q1.y, q1.x, 0x07060302u);
  hi.w = __builtin_amdgcn_perm(q1.w, q1.z, 0x07060302u);
  *(uint4*)dlo = lo;
  *(uint4*)dhi = hi;
}

// ---------------------------------------------------------------------------
// bf16 MFMA GEMM over t-pair-packed activations (out-of-place ping-pong):
//   z[t,b,o] = sum_k s[t,b,k] * W[o,k] + bias[o],  N = 512 fixed.
// R22-proven structure: 512 threads (8 waves), wave = 64 rows x 64 cols;
// planar-bf16 LDS staging (store-side destage), 1-term MFMA with single
// bf16 W in pre-swizzled fragment order + RING-4 register prefetch.
// R23's ring-8 SPILLED (acc 64 + ring 64 + misc > 128-VGPR cap at 4
// waves/SIMD -> scratch traffic, FETCH 37->213 MB, 4x slower). Ring-4 is
// the register-budget optimum. Coalesced epilogue via LDS funnel.
// W fragment layout: elem (o,k) at ((c32*NIT+itg)*64 + kg*32 + r31)*8 + j.
// Also zeroes stats[0..1023] from block 0 (bn_fold precedes in stream order).
// ---------------------------------------------------------------------------
#define ROWS 64

template <int K, int BKC, bool PACKED_IN>
__global__ __launch_bounds__(512, 4) void gemm_mfma(
    const void* src, const unsigned short* __restrict__ Whi,
    const float* __restrict__ bias, uint* __restrict__ dstP, float* stats) {
  constexpr int NC = K / BKC;      // 2 (layer 0) or 4 (K=512)
  constexpr int NITC = BKC / 16;   // MFMA k-steps per chunk
  constexpr int NIT = K / 16;
  constexpr int GM = BKC / 8 - 1;  // granule swizzle mask
  __shared__ __align__(16) unsigned short AhS[2][ROWS * BKC];

  const int tid = threadIdx.x;
  if (blockIdx.x == 0) {  // fold zero_stats into the GEMM
    stats[tid] = 0.f;
    stats[tid + 512] = 0.f;
  }
  const int lane = tid & 63;
  const int wave = tid >> 6;  // 0..7 = col-group of 64
  const int r31 = lane & 31;
  const int kg = lane >> 5;

  const size_t pbase = (size_t)blockIdx.x * 16384;  // block's u32 region
  const uint* srcP = (const uint*)src;
  const float* srcF = (const float*)src;
  const size_t row0 = (size_t)blockIdx.x * ROWS;  // f32-path row base

  const unsigned short* pWh0 =
      Whi + ((size_t)(wave * 2 + 0) * NIT * 64 + lane) * 8;
  const unsigned short* pWh1 =
      Whi + ((size_t)(wave * 2 + 1) * NIT * 64 + lane) * 8;

  const int sr0 = tid >> 4, sk0 = tid & 15;
  const int ss0 = sr0 * BKC + ((sk0 ^ (sr0 & GM)) << 3);
  const int ss1 = (sr0 + 32) * BKC + ((sk0 ^ ((sr0 + 32) & GM)) << 3);
  const int srf = tid >> 3, skf = tid & 7;
  const int ssf = srf * BKC + ((skf ^ (srf & GM)) << 3);

  auto cvt8 = [&](float4 a, float4 b) {
    float vv[8] = {a.x, a.y, a.z, a.w, b.x, b.y, b.z, b.w};
    s16x8 hi;
#pragma unroll
    for (int j = 0; j < 8; ++j) hi[j] = (short)f2bf(vv[j]);
    return hi;
  };

  // ---- prologue: stage chunk 0 ----
  if (PACKED_IN) {
    uint4 q0 = *(const uint4*)(srcP + pbase + sr0 * 512 + sk0 * 8);
    uint4 q1 = *(const uint4*)(srcP + pbase + sr0 * 512 + sk0 * 8 + 4);
    destage(q0, q1, &AhS[0][ss0], &AhS[0][ss1]);
  } else {
    const size_t g = (row0 + srf) * K + skf * 8;
    *(s16x8*)&AhS[0][ssf] =
        cvt8(*(const float4*)(srcF + g), *(const float4*)(srcF + g + 4));
  }
  // ---- W ring prologue: fragments itg=0,1,2 into slots 0,1,2 ----
  s16x8 whr[4][2];
#pragma unroll
  for (int s = 0; s < 3; ++s) {
    whr[s][0] = *(const s16x8*)(pWh0 + (size_t)s * 512);
    whr[s][1] = *(const s16x8*)(pWh1 + (size_t)s * 512);
  }
  __syncthreads();

  f32x16 acc[2][2] = {};
  uint4 q0, q1;   // in-flight next-chunk A (packed)
  float4 f0, f1;  // in-flight next-chunk A (f32)
#pragma unroll
  for (int c = 0; c < NC; ++c) {
    if (c + 1 < NC) {  // issue next chunk's loads (hide under MFMAs)
      if (PACKED_IN) {
        q0 = *(const uint4*)(srcP + pbase + sr0 * 512 + (c + 1) * BKC +
                             sk0 * 8);
        q1 = *(const uint4*)(srcP + pbase + sr0 * 512 + (c + 1) * BKC +
                             sk0 * 8 + 4);
      } else {
        const size_t g = (row0 + srf) * K + (c + 1) * BKC + skf * 8;
        f0 = *(const float4*)(srcF + g);
        f1 = *(const float4*)(srcF + g + 4);
      }
    }
    const int bsel = c & 1;
#pragma unroll
    for (int it = 0; it < NITC; ++it) {
      const int itg = c * NITC + it;
      const int sl = itg & 3;
      if (itg + 3 < NIT) {  // ring-4 W prefetch (3-step lookahead)
        const int sp = (itg + 3) & 3;
        whr[sp][0] = *(const s16x8*)(pWh0 + (size_t)(itg + 3) * 512);
        whr[sp][1] = *(const s16x8*)(pWh1 + (size_t)(itg + 3) * 512);
      }
      const int gi = it * 2 + kg;
      s16x8 ah[2];
#pragma unroll
      for (int rf = 0; rf < 2; ++rf) {
        const int row = rf * 32 + r31;
        ah[rf] =
            *(const s16x8*)&AhS[bsel][row * BKC + ((gi ^ (row & GM)) << 3)];
      }
#pragma unroll
      for (int cf = 0; cf < 2; ++cf)
#pragma unroll
        for (int rf = 0; rf < 2; ++rf)
          acc[rf][cf] = __builtin_amdgcn_mfma_f32_32x32x16_bf16(
              ah[rf], whr[sl][cf], acc[rf][cf], 0, 0, 0);
    }
    if (c + 1 < NC) {  // stage next chunk into the other LDS buffer
      const int nb = (c + 1) & 1;
      if (PACKED_IN) {
        destage(q0, q1, &AhS[nb][ss0], &AhS[nb][ss1]);
      } else {
        *(s16x8*)&AhS[nb][ssf] = cvt8(f0, f1);
      }
      __syncthreads();
    }
  }

  // ---- epilogue (coalesced via LDS funnel) ----
  {
    uint* Cs = (uint*)&AhS[0][0];
    constexpr int CAP = ROWS * BKC;
    constexpr int RP = CAP / 512;
    constexpr int NP = 32 / RP;
    constexpr int NQ = CAP / 2048;
    const int o0 = wave * 64 + r31;
    const float bb0 = bias[o0];
    const float bb1 = bias[o0 + 32];
    __syncthreads();
#pragma unroll
    for (int p = 0; p < NP; ++p) {
#pragma unroll
      for (int j = 0; j < RP / 2; ++j) {
        const int r = p * (RP / 2) + j;
        const int mb = (r & 3) + 8 * (r >> 2) + 4 * kg;
        const int lr = mb - p * RP;
        const float e0 = acc[0][0][r] + bb0;
        const float d0 = acc[1][0][r] + bb0;
        const float e1 = acc[0][1][r] + bb1;
        const float d1 = acc[1][1][r] + bb1;
        Cs[lr * 512 + o0] = (uint)f2bf(e0) | ((uint)f2bf(d0) << 16);
        Cs[lr * 512 + o0 + 32] = (uint)f2bf(e1) | ((uint)f2bf(d1) << 16);
      }
      __syncthreads();
#pragma unroll
      for (int qd = 0; qd < NQ; ++qd) {
        uint4 v = *(const uint4*)&Cs[qd * 2048 + tid * 4];
        *(uint4*)&dstP[pbase + (size_t)p * CAP + qd * 2048 + tid * 4] = v;
      }
      if (p + 1 < NP) __syncthreads();
    }
  }
}

// ---------------------------------------------------------------------------
// FUSED segmented scan (R22 structure + R23 LDS-reduced stats atomics).
// h_t = max(z_t + u h_{t-1}, 0) composes as F(h)=max(A+B h, G).
// Block = 64 consecutive chains x all 16 segments (1024 threads, 16 waves;
// wave = one segment x 64 chains -> coalesced 256B/instr). Per thread:
// load segment's 64 packed u32 into REGISTERS, fold (A,G), LDS-exchange,
// serial exclusive combine with B=u^128, replay from registers, write
// packed bf16 s. Stats reduced across the 16 segments in LDS first ->
// 16x fewer atomics (2048 -> 128 per block over 512 hot addresses).
// ---------------------------------------------------------------------------
__global__ __launch_bounds__(1024, 4) void indrnn_scan_seg(
    const uint* __restrict__ z, uint* __restrict__ sdst,
    const float* __restrict__ u, float* __restrict__ stats) {
  __shared__ float Als[NSEG * 64];
  __shared__ float Gls[NSEG * 64];
  const int tid = threadIdx.x;
  const int j = tid >> 6;   // segment 0..15 (wave-uniform)
  const int cl = tid & 63;  // chain-in-block
  const int c = blockIdx.x * 64 + cl;
  const int hch = c & (H_DIM - 1);
  const float uu = u[hch];
  const uint* ps = z + c + (size_t)j * SEGI * NCH_CHAINS;
  uint* pd = sdst + c + (size_t)j * SEGI * NCH_CHAINS;

  // ---- load whole segment into registers ----
  uint v[SEGI];
#pragma unroll
  for (int q = 0; q < SEGI; ++q) v[q] = ps[(size_t)q * NCH_CHAINS];

  // ---- phase A: fold segment map (A = linear part, G = floor) ----
  float A = 0.f, G = -1.0e30f;
#pragma unroll
  for (int q = 0; q < SEGI; ++q) {
    const uint pk = v[q];
    const float ze = __uint_as_float(pk << 16);
    const float zo = __uint_as_float(pk & 0xffff0000u);
    A = fmaf(uu, A, ze);
    G = fmaxf(fmaf(uu, G, ze), 0.f);
    A = fmaf(uu, A, zo);
    G = fmaxf(fmaf(uu, G, zo), 0.f);
  }
  Als[tid] = A;  // row j, col cl
  Gls[tid] = G;
  __syncthreads();

  // ---- exclusive combine: incoming h for segment j ----
  float B = uu;
#pragma unroll
  for (int q = 0; q < 7; ++q) B *= B;  // u^128
  float hh = 0.f;
  for (int jp = 0; jp < j; ++jp)  // wave-uniform trip count
    hh = fmaxf(fmaf(B, hh, Als[jp * 64 + cl]), Gls[jp * 64 + cl]);
  __syncthreads();  // all combine reads done before Als/Gls reuse below

  // ---- phase C: replay from registers, write packed bf16 s ----
  float sum = 0.f, sumsq = 0.f;
#pragma unroll
  for (int q = 0; q < SEGI; ++q) {
    const uint pk = v[q];
    const float ze = __uint_as_float(pk << 16);
    const float zo = __uint_as_float(pk & 0xffff0000u);
    hh = fmaxf(ze + uu * hh, 0.f);
    const unsigned short he = f2bf(hh);
    const float se = bf2f(he);
    sum += se;
    sumsq += se * se;
    hh = fmaxf(zo + uu * hh, 0.f);
    const unsigned short ho = f2bf(hh);
    const float so = bf2f(ho);
    sum += so;
    sumsq += so * so;
    pd[(size_t)q * NCH_CHAINS] = (uint)he | ((uint)ho << 16);
  }
  // ---- stats: reduce across segments in LDS, 1 atomic pair per chain ----
  Als[tid] = sum;
  Gls[tid] = sumsq;
  __syncthreads();
  if (j == 0) {
    float ts = 0.f, tq = 0.f;
#pragma unroll
    for (int jp = 0; jp < NSEG; ++jp) {
      ts += Als[jp * 64 + cl];
      tq += Gls[jp * 64 + cl];
    }
    atomicAdd(&stats[hch], ts);
    atomicAdd(&stats[H_DIM + hch], tq);
  }
}

__global__ __launch_bounds__(64) void fill_sentinel(float* __restrict__ out,
                                                    int n) {
  for (int i = threadIdx.x; i < n; i += 64) out[i] = 1.0e6f;
}

// ---------------------------------------------------------------------------
// Convert raw f32 weights (layer 0) to bf16 in fragment-swizzled order.
// ---------------------------------------------------------------------------
template <int K>
__global__ __launch_bounds__(256) void convert_w(
    const float* __restrict__ W, unsigned short* __restrict__ Whi) {
  constexpr int NIT = K / 16;
  int i = blockIdx.x * 256 + threadIdx.x;
  if (i < H_DIM * K) {
    int o = i / K, k = i % K;
    size_t idx =
        ((size_t)((o >> 5) * NIT + (k >> 4)) * 64 + ((k >> 3) & 1) * 32 +
         (o & 31)) * 8 + (k & 7);
    Whi[idx] = f2bf(W[i]);
  }
}

// ---------------------------------------------------------------------------
// Fold BN of previous layer into next layer's weights, emit swizzled bf16.
// ---------------------------------------------------------------------------
__global__ __launch_bounds__(256) void bn_fold(
    const float* __restrict__ stats, const float* __restrict__ gamma,
    const float* __restrict__ beta, const float* __restrict__ Wn,
    const float* __restrict__ bn, unsigned short* __restrict__ Whi,
    float* __restrict__ bf) {
  constexpr int NIT = H_DIM / 16;
  const int o = blockIdx.x;
  const int tid = threadIdx.x;
  constexpr float invTB = 1.f / (float)(T_DIM * B_DIM);
  float part = 0.f;
  for (int i = tid; i < H_DIM; i += 256) {
    float mean = stats[i] * invTB;
    float var = stats[H_DIM + i] * invTB - mean * mean;
    float a = gamma[i] * rsqrtf(var + BN_EPS);
    float c = beta[i] - mean * a;
    float w = Wn[(size_t)o * H_DIM + i];
    size_t idx =
        ((size_t)((o >> 5) * NIT + (i >> 4)) * 64 + ((i >> 3) & 1) * 32 +
         (o & 31)) * 8 + (i & 7);
    Whi[idx] = f2bf(w * a);
    part += w * c;
  }
  __shared__ float red[256];
  red[tid] = part;
  __syncthreads();
  for (int s = 128; s > 0; s >>= 1) {
    if (tid < s) red[tid] += red[tid + s];
    __syncthreads();
  }
  if (tid == 0) bf[o] = bn[o] + red[0];
}

// ---------------------------------------------------------------------------
// Final: out[b,c] = sum_i (s5[T-1,b,i]*a5[i] + c5[i]) * Wout[c,i] + bout[c]
// ---------------------------------------------------------------------------
__global__ __launch_bounds__(64) void final_out(const uint* __restrict__ s5,
                                                const float* __restrict__ stats,
                                                const float* __restrict__ gamma,
                                                const float* __restrict__ beta,
                                                const float* __restrict__ Wout,
                                                const float* __restrict__ bout,
                                                float* __restrict__ out) {
  const int b = blockIdx.x / C_DIM, cls = blockIdx.x % C_DIM;
  const int lane = threadIdx.x;
  constexpr float invTB = 1.f / (float)(T_DIM * B_DIM);
  const uint* srow =
      s5 + (size_t)(T_DIM / 2 - 1) * B_DIM * H_DIM + (size_t)b * H_DIM;
  float part = 0.f;
  for (int i = lane; i < H_DIM; i += 64) {
    float mean = stats[i] * invTB;
    float var = stats[H_DIM + i] * invTB - mean * mean;
    float a = gamma[i] * rsqrtf(var + BN_EPS);
    float c = beta[i] - mean * a;
    float sval = __uint_as_float(srow[i] & 0xffff0000u);
    part += (sval * a + c) * Wout[(size_t)cls * H_DIM + i];
  }
#pragma unroll
  for (int off = 32; off > 0; off >>= 1) part += __shfl_down(part, off);
  if (lane == 0) out[b * C_DIM + cls] = part + bout[cls];
}

// ---------------------------------------------------------------------------
extern "C" void kernel_launch(void* const* d_in, const int* in_sizes, int n_in,
                              void* d_out, int out_size, void* d_ws,
                              size_t ws_size, hipStream_t stream) {
  const float* x     = (const float*)d_in[0];
  const float* W0    = (const float*)d_in[1];
  const float* b0    = (const float*)d_in[2];
  const float* Wh    = (const float*)d_in[3];
  const float* bh    = (const float*)d_in[4];
  const float* u     = (const float*)d_in[5];
  const float* gamma = (const float*)d_in[6];
  const float* beta  = (const float*)d_in[7];
  const float* Wout  = (const float*)d_in[8];
  const float* bout  = (const float*)d_in[9];
  float* out = (float*)d_out;

  const size_t need = 2 * PKN * sizeof(uint) +
                      (size_t)H_DIM * H_DIM * sizeof(unsigned short) +
                      3 * H_DIM * sizeof(float);
  if (ws_size < need) {
    fill_sentinel<<<1, 64, 0, stream>>>(out, out_size);
    return;
  }

  uint* bufA = (uint*)d_ws;                             // 64 MB: z
  uint* bufB = bufA + PKN;                              // 64 MB: s
  unsigned short* Whi = (unsigned short*)(bufB + PKN);  // 512 KB
  float* bf = (float*)(Whi + (size_t)H_DIM * H_DIM);    // 2 KB
  float* stats = bf + H_DIM;                            // 4 KB

  const int gemm_blocks = TB / ROWS;        // 1024
  const int scan_blocks = NCH_CHAINS / 64;  // 256 blocks x 1024 threads

  // ---- layer 0: x (f32, K=128, BKC=64 -> NC=2 pipelined) -> bufA (z) ----
  convert_w<D_DIM><<<(H_DIM * D_DIM + 255) / 256, 256, 0, stream>>>(W0, Whi);
  gemm_mfma<D_DIM, 64, false><<<gemm_blocks, 512, 0, stream>>>(x, Whi, b0,
                                                               bufA, stats);
  indrnn_scan_seg<<<scan_blocks, 1024, 0, stream>>>(bufA, bufB, u, stats);

  // ---- layers 1..5: ping-pong (s in B -> z in A -> s in B) ----
  for (int l = 1; l < L_DIM; ++l) {
    const float* ul = u + (size_t)l * H_DIM;
    bn_fold<<<H_DIM, 256, 0, stream>>>(
        stats, gamma + (size_t)(l - 1) * H_DIM, beta + (size_t)(l - 1) * H_DIM,
        Wh + (size_t)(l - 1) * H_DIM * H_DIM, bh + (size_t)(l - 1) * H_DIM,
        Whi, bf);
    gemm_mfma<H_DIM, 128, true><<<gemm_blocks, 512, 0, stream>>>(
        bufB, Whi, bf, bufA, stats);
    indrnn_scan_seg<<<scan_blocks, 1024, 0, stream>>>(bufA, bufB, ul, stats);
  }

  // ---- final projection (BN of layer 5 applied on the fly) ----
  final_out<<<B_DIM * C_DIM, 64, 0, stream>>>(
      bufB, stats, gamma + 5 * (size_t)H_DIM, beta + 5 * (size_t)H_DIM, Wout,
      bout, out);
}